// Round 15
// baseline (210.889 us; speedup 1.0000x reference)
//
#include <hip/hip_runtime.h>

// Problem constants
#define MROWS 512            // B*S
#define VDIM  50257          // vocab
#define KP    50304          // VDIM padded to multiple of 64 (= 64*786)
#define NDIM  1024           // D
#define NST32 1572           // KP/32 K-steps of 32
#define KSPLIT 48
#define PRED_OFF 524288      // 512*1024
#define PP_OFF   524800      // + 512
#define NPREP  4096          // 512 rows x 8 chunks
#define CHUNK  6288          // multiple of 8; 8*6288 >= VDIM
#define NCONVW 6288          // 393 v-pairs * 16 d-tiles

typedef unsigned short u16;
typedef unsigned int   u32;
typedef unsigned long long u64;
typedef __bf16 bf16x8 __attribute__((ext_vector_type(8)));
typedef u16    u16x8  __attribute__((ext_vector_type(8)));
typedef float  f32x4  __attribute__((ext_vector_type(4)));
typedef float  f32x4u __attribute__((ext_vector_type(4), aligned(4)));

__device__ __forceinline__ u16 f2bf(float f) {
  u32 u = __float_as_uint(f);
  u32 r = (u + 0x7fffu + ((u >> 16) & 1u)) >> 16;  // RNE
  return (u16)r;
}

__device__ __forceinline__ float bf2f(u16 v) {
  return __uint_as_float((u32)v << 16);
}

__device__ __forceinline__ void gl_lds16(const u16* g, u16* l) {
  __builtin_amdgcn_global_load_lds(
      (const __attribute__((address_space(1))) u32*)(g),
      (__attribute__((address_space(3))) u32*)(l), 16, 0, 0);
}

// ---------------------------------------------------------------------------
// prep: P row-chunks (copy + argmax + bf16, single pass, 8-elem groups ->
// 16B A-stores, 4 loads in flight). Argmax partial -> plain store to part[].
// ---------------------------------------------------------------------------
__global__ __launch_bounds__(256) void prep_kernel(const float* __restrict__ P,
                                                   float* __restrict__ out,
                                                   u16* __restrict__ A,
                                                   u64* __restrict__ part)
{
  const int tid = threadIdx.x;
  const int bx  = blockIdx.x;
  const int m  = bx >> 3;
  const int c  = bx & 7;
  const int s0 = c * CHUNK;
  const int len = min(VDIM - s0, CHUNK);       // 6288, last chunk 6241
  const float* row = P + (size_t)m * VDIM;
  float*       crw = out + PP_OFF + (size_t)m * VDIM;
  u16*        arow = A + (size_t)m * KP;

  if (tid < 32) { f32x4 z = {}; *(f32x4*)(out + (size_t)m * NDIM + c * 128 + tid * 4) = z; }

  u64 best = 0;  // packed (f32 bits << 32) | (0xFFFF - idx); p>0 so bits>0
#define TRK(val, idx) do { \
    u64 pk = ((u64)__float_as_uint(val) << 32) | (u64)(0xFFFFu - (u32)(idx)); \
    best = best > pk ? best : pk; } while (0)
#define GRP(cc) do {                                                     \
    f32x4u va = *(const f32x4u*)(row + (cc));                            \
    f32x4u vb = *(const f32x4u*)(row + (cc) + 4);                        \
    *(f32x4u*)(crw + (cc))     = va;                                     \
    *(f32x4u*)(crw + (cc) + 4) = vb;                                     \
    u16x8 o;                                                             \
    o[0]=f2bf(va[0]); o[1]=f2bf(va[1]); o[2]=f2bf(va[2]); o[3]=f2bf(va[3]); \
    o[4]=f2bf(vb[0]); o[5]=f2bf(vb[1]); o[6]=f2bf(vb[2]); o[7]=f2bf(vb[3]); \
    *(u16x8*)(arow + (cc)) = o;                                          \
    TRK(va[0],(cc)); TRK(va[1],(cc)+1); TRK(va[2],(cc)+2); TRK(va[3],(cc)+3); \
    TRK(vb[0],(cc)+4); TRK(vb[1],(cc)+5); TRK(vb[2],(cc)+6); TRK(vb[3],(cc)+7); \
  } while (0)

  const int ng = len >> 3;                     // 8-elem groups
  int i = tid;
  for (; i + 256 < ng; i += 512) {             // 4 loads in flight
    const int c0 = s0 + (i << 3);
    const int c1 = c0 + 2048;
    GRP(c0);
    GRP(c1);
  }
  if (i < ng) GRP(s0 + (i << 3));
  if (tid < (len & 7)) {                       // straggler elems (last chunk)
    const int col = s0 + (ng << 3) + tid;
    float v = row[col];
    crw[col] = v;
    arow[col] = f2bf(v);
    TRK(v, col);
  }
#undef GRP
#undef TRK
  if (c == 7 && tid < KP - VDIM) arow[VDIM + tid] = 0;  // K-pad (47 elems)

  __shared__ u64 sb[256];
  sb[tid] = best;
  __syncthreads();
  for (int s = 128; s > 0; s >>= 1) {
    if (tid < s) { u64 o = sb[tid + s]; if (o > sb[tid]) sb[tid] = o; }
    __syncthreads();
  }
  if (tid == 0) part[(m << 3) + c] = sb[0];    // plain store, always written
}

// ---------------------------------------------------------------------------
// convw: transpose+convert W [V][D] f32 -> ks-BLOCKED BT'[ks][1024][32] bf16
// (ks = v/32). Two adjacent 64x64 v-tiles per block = 4 ks-blocks; stores are
// 4 x 4KB fully contiguous chunks (R14-validated, +5us).
// ---------------------------------------------------------------------------
__global__ __launch_bounds__(256) void convw_kernel(const float* __restrict__ W,
                                                    u16* __restrict__ BT)
{
  __shared__ u16 tA[64][72];
  __shared__ u16 tB[64][72];
  const int cidx = blockIdx.x;        // 0..6287
  const int tid = threadIdx.x;
  const int dt  = cidx & 15;          // 16 d-tiles of 64
  const int vp  = cidx >> 4;          // 0..392 v-pairs; 393*128 == KP exactly
  const int v0  = vp << 7;
  const int d0  = dt << 6;
  const int c16 = tid & 15;
  const int r16 = tid >> 4;
#pragma unroll
  for (int p = 0; p < 4; ++p) {
    const int vl = p * 16 + r16;
    {
      const int v = v0 + vl;
      float4 w = make_float4(0.f, 0.f, 0.f, 0.f);
      if (v < VDIM) w = *(const float4*)(W + (size_t)v * NDIM + d0 + c16 * 4);
      tA[c16 * 4 + 0][vl] = f2bf(w.x);
      tA[c16 * 4 + 1][vl] = f2bf(w.y);
      tA[c16 * 4 + 2][vl] = f2bf(w.z);
      tA[c16 * 4 + 3][vl] = f2bf(w.w);
    }
    {
      const int v = v0 + 64 + vl;
      float4 w = make_float4(0.f, 0.f, 0.f, 0.f);
      if (v < VDIM) w = *(const float4*)(W + (size_t)v * NDIM + d0 + c16 * 4);
      tB[c16 * 4 + 0][vl] = f2bf(w.x);
      tB[c16 * 4 + 1][vl] = f2bf(w.y);
      tB[c16 * 4 + 2][vl] = f2bf(w.z);
      tB[c16 * 4 + 3][vl] = f2bf(w.w);
    }
  }
  __syncthreads();
  const int dl = tid >> 2;            // 0..63
  const int kq = tid & 3;             // 0..3 (8 elems each)
#pragma unroll
  for (int kb = 0; kb < 4; ++kb) {
    const u16* src = (kb < 2) ? &tA[dl][kb * 32 + kq * 8]
                              : &tB[dl][(kb - 2) * 32 + kq * 8];
    u16x8 o = *(const u16x8*)src;     // 16B-aligned (144B rows, offsets x16B)
    *(u16x8*)(BT + (size_t)((v0 >> 5) + kb) * 32768
                 + (size_t)(d0 + dl) * 32 + kq * 8) = o;
  }
}

// ---------------------------------------------------------------------------
// GEMM (R10/R14-proven schedule): 128x256 tile, BK=32, 8 waves (2m x 4n),
// ring-2 LDS (48KB -> 3 blocks/CU at grid 768: staging-rate scales with
// resident blocks, R8/R9 evidence), single barrier + vmcnt(0) per K-step with
// full-compute prefetch slack, paired-row 8-slot XOR swizzle (0 conflicts),
// split-K=48, XCD decode, blocked-BT' B reads (1KB contiguous per issue).
// TS=1: bf16 partial stores to Pp (halves epilogue bytes; partials ~1.6e-5
// scale so bf16 err ~3e-7 accumulated, well under budget). TS=0: f32 atomics.
// Block 0 also finalizes predictions from part[].
// ---------------------------------------------------------------------------
template <int TS>
__global__ __launch_bounds__(512, 4) void gemm_kernel(const u16* __restrict__ A,
                                                      const u16* __restrict__ BT,
                                                      const u64* __restrict__ part,
                                                      float* __restrict__ out,
                                                      u16* __restrict__ Pp)
{
  __shared__ u16 ldsA[2][128 * 32];   // 8KB per buf
  __shared__ u16 ldsB[2][256 * 32];   // 16KB per buf

  const int bx  = blockIdx.x;
  // decode: bx = ((kc>>3)*16 + mn)*8 + (kc&7); the 16 mn-blocks of one kc
  // share bx%8 -> same XCD (kc's A/B k-slabs stay in one L2)
  const int x   = bx & 7;
  const int s   = bx >> 3;
  const int kc  = x + ((s >> 4) << 3);   // 0..47
  const int mn  = s & 15;
  const int mt  = mn & 3;                // 4 m-tiles of 128
  const int nt  = mn >> 2;               // 4 n-tiles of 256
  const int m0  = mt << 7;
  const int n0  = nt << 8;
  const int ks0 = (kc * NST32) / KSPLIT;
  const int ks1 = ((kc + 1) * NST32) / KSPLIT;
  const int tid  = threadIdx.x;
  const int wid  = tid >> 6;
  const int lane = tid & 63;
  const int wr   = wid >> 2;   // 0..1  (m-offset wr*64)
  const int wc   = wid & 3;    // 0..3  (n-offset wc*64)

  if (bx == 0) {  // predictions: reduce 8 chunk-partials per row
    u64 best = part[tid << 3];
#pragma unroll
    for (int c = 1; c < 8; ++c) {
      u64 o = part[(tid << 3) + c];
      best = o > best ? o : best;
    }
    out[PRED_OFF + tid] = (float)(0xFFFF - (int)(best & 0xFFFFu));
  }

  // staging (pre-swizzled source): lane l = sp*8+s covers 16B slot s of 128B
  // row-pair sp within a 16-row issue; LDS written linearly; slot s of pair
  // sp holds global (row 2sp+((s^sp)>>2), kslot (s^sp)&3)  [validated R6-R14]
  const int sp   = lane >> 3;
  const int sx   = (lane & 7) ^ sp;
  const int srow = 2 * sp + (sx >> 2);        // 0..15
  const int skel = (sx & 3) << 3;
  const u16* gA = A  + (size_t)(m0 + wid * 16 + srow) * KP + skel;
  // blocked B: row stride 32 elems within a ks-frame of 1024*32 elems
  const u16* gB = BT + (size_t)(n0 + wid * 32 + srow) * 32 + skel;

  f32x4 acc[4][4] = {};

  // fragment read: row r in 16-band, kslot q4 -> swizzled slot sl
  const int r   = lane & 15;
  const int q4  = lane >> 4;
  const int sl  = (((r & 1) << 2) | q4) ^ ((r >> 1) & 7);
  const int rb2A = (wr * 64 + (r & ~1)) * 32 + sl * 8;
  const int rb2B = (wc * 64 + (r & ~1)) * 32 + sl * 8;

#define STAGE(buf, ks) do {                                              \
    gl_lds16(gA + ((size_t)(ks) << 5),     &ldsA[buf][(wid * 16) * 32]); \
    const size_t bb = (size_t)(ks) * 32768;                              \
    gl_lds16(gB + bb,                      &ldsB[buf][(wid * 32) * 32]); \
    gl_lds16(gB + bb + 512,                &ldsB[buf][(wid * 32 + 16) * 32]); \
  } while (0)

  STAGE(0, ks0);

  int b = 0;
  for (int ks = ks0; ks < ks1; ++ks) {
    asm volatile("s_waitcnt vmcnt(0)" ::: "memory");  // buf b landed (mine)
    __builtin_amdgcn_s_barrier();                     // ..and everyone's;
                                                      // also: reads of b^1 done
    if (ks + 1 < ks1) STAGE(b ^ 1, ks + 1);           // prefetch next step

    const u16* lA = ldsA[b];
    const u16* lB = ldsB[b];
    bf16x8 av[4], bv[4];
#pragma unroll
    for (int i = 0; i < 4; ++i) av[i] = *(const bf16x8*)(lA + rb2A + i * 512);
#pragma unroll
    for (int j = 0; j < 4; ++j) bv[j] = *(const bf16x8*)(lB + rb2B + j * 512);

    __builtin_amdgcn_s_setprio(1);
#pragma unroll
    for (int i = 0; i < 4; ++i)
#pragma unroll
      for (int j = 0; j < 4; ++j)
        acc[i][j] = __builtin_amdgcn_mfma_f32_16x16x32_bf16(av[i], bv[j], acc[i][j], 0, 0, 0);
    __builtin_amdgcn_s_setprio(0);
    __builtin_amdgcn_sched_barrier(0);
    b ^= 1;
  }
#undef STAGE

  const int col = lane & 15;
  if (TS) {
    // bf16 partial-tile store: Pp[bx][128][256]
    u16* pp = Pp + (size_t)bx * 32768;
#pragma unroll
    for (int i = 0; i < 4; ++i)
#pragma unroll
      for (int j = 0; j < 4; ++j)
#pragma unroll
        for (int rr = 0; rr < 4; ++rr) {
          const int mm = wr * 64 + i * 16 + q4 * 4 + rr;
          const int nn = wc * 64 + j * 16 + col;
          pp[mm * 256 + nn] = f2bf(acc[i][j][rr]);
        }
  } else {
#pragma unroll
    for (int i = 0; i < 4; ++i)
#pragma unroll
      for (int j = 0; j < 4; ++j)
#pragma unroll
        for (int rr = 0; rr < 4; ++rr) {
          const int mm = m0 + wr * 64 + i * 16 + q4 * 4 + rr;
          const int nn = n0 + wc * 64 + j * 16 + col;
          atomicAdd(out + (size_t)mm * NDIM + nn, acc[i][j][rr]);
        }
  }
}

// ---------------------------------------------------------------------------
// reduce: out[m][n] = sum over 48 kc-partials (bf16). 512 blocks x 256 thr;
// each thread owns one n-quad: 48 coalesced 8B loads + cvt, f32 accumulate.
// ---------------------------------------------------------------------------
__global__ __launch_bounds__(256) void reduce_kernel(const u16* __restrict__ Pp,
                                                     float* __restrict__ out)
{
  const int t   = blockIdx.x * 256 + threadIdx.x;  // 0..131071
  const int m   = t >> 8;                          // 0..511
  const int n0q = (t & 255) << 2;                  // 0..1020
  const int mt  = m >> 7;                          // 0..3
  const int nt  = n0q >> 8;                        // 0..3
  const size_t base = (size_t)(m & 127) * 256 + (n0q & 255);

  f32x4 sacc[2] = {};
#pragma unroll
  for (int kc = 0; kc < KSPLIT; ++kc) {
    const int bxp = (((kc >> 3) * 16 + (nt << 2) + mt) << 3) + (kc & 7);
    ushort4 v = *(const ushort4*)(Pp + (size_t)bxp * 32768 + base);
    f32x4 f = { bf2f(v.x), bf2f(v.y), bf2f(v.z), bf2f(v.w) };
    sacc[kc & 1] += f;
  }
  f32x4 rsum = sacc[0] + sacc[1];
  *(f32x4*)(out + (size_t)m * NDIM + n0q) = rsum;
}

// ---------------------------------------------------------------------------
extern "C" void kernel_launch(void* const* d_in, const int* in_sizes, int n_in,
                              void* d_out, int out_size, void* d_ws, size_t ws_size,
                              hipStream_t stream) {
  const float* P = (const float*)d_in[0];   // [512][50257]
  const float* W = (const float*)d_in[1];   // [50257][1024]
  float* out = (float*)d_out;
  u64* part = (u64*)d_ws;                               // 512 x 8 u64 (32KB)
  u16* A  = (u16*)((char*)d_ws + 65536);                // [512][KP] bf16
  u16* BT = A + (size_t)MROWS * KP;                     // BT'[1572][1024][32] bf16
  const size_t pp_off = 65536 + (size_t)MROWS * KP * 2 + (size_t)NDIM * KP * 2;
  const size_t pp_bytes = (size_t)768 * 32768 * 2;      // 50.3 MB (bf16)
  u16* Pp = (u16*)((char*)d_ws + pp_off);
  const bool two_stage = (ws_size >= pp_off + pp_bytes);

  prep_kernel<<<NPREP, 256, 0, stream>>>(P, out, A, part);
  convw_kernel<<<NCONVW, 256, 0, stream>>>(W, BT);
  if (two_stage) {
    gemm_kernel<1><<<768, 512, 0, stream>>>(A, BT, part, out, Pp);
    reduce_kernel<<<512, 256, 0, stream>>>(Pp, out);
  } else {
    gemm_kernel<0><<<768, 512, 0, stream>>>(A, BT, part, out, Pp);
  }
}

// Round 16
// 196.049 us; speedup vs baseline: 1.0757x; 1.0757x over previous
//
#include <hip/hip_runtime.h>

// Problem constants
#define MROWS 512            // B*S
#define VDIM  50257          // vocab
#define KP    50304          // VDIM padded to multiple of 64 (= 64*786)
#define NDIM  1024           // D
#define NST32 1572           // KP/32 K-steps of 32
#define KSPLIT 32
#define PRED_OFF 524288      // 512*1024
#define PP_OFF   524800      // + 512
#define NPREP  4096          // 512 rows x 8 chunks
#define CHUNK  6288          // multiple of 8; 8*6288 >= VDIM
#define NCONVW 6288          // 393 v-pairs * 16 d-tiles

typedef unsigned short u16;
typedef unsigned int   u32;
typedef unsigned long long u64;
typedef __bf16 bf16x8 __attribute__((ext_vector_type(8)));
typedef u16    u16x8  __attribute__((ext_vector_type(8)));
typedef float  f32x4  __attribute__((ext_vector_type(4)));
typedef float  f32x4u __attribute__((ext_vector_type(4), aligned(4)));

__device__ __forceinline__ u16 f2bf(float f) {
  u32 u = __float_as_uint(f);
  u32 r = (u + 0x7fffu + ((u >> 16) & 1u)) >> 16;  // RNE
  return (u16)r;
}

__device__ __forceinline__ float bf2f(u16 v) {
  return __uint_as_float((u32)v << 16);
}

__device__ __forceinline__ void gl_lds16(const u16* g, u16* l) {
  __builtin_amdgcn_global_load_lds(
      (const __attribute__((address_space(1))) u32*)(g),
      (__attribute__((address_space(3))) u32*)(l), 16, 0, 0);
}

// ---------------------------------------------------------------------------
// prep: P row-chunks (copy + argmax + bf16, single pass, 8-elem groups ->
// 16B A-stores, 4 loads in flight). Argmax partial -> plain store to part[].
// ---------------------------------------------------------------------------
__global__ __launch_bounds__(256) void prep_kernel(const float* __restrict__ P,
                                                   float* __restrict__ out,
                                                   u16* __restrict__ A,
                                                   u64* __restrict__ part)
{
  const int tid = threadIdx.x;
  const int bx  = blockIdx.x;
  const int m  = bx >> 3;
  const int c  = bx & 7;
  const int s0 = c * CHUNK;
  const int len = min(VDIM - s0, CHUNK);       // 6288, last chunk 6241
  const float* row = P + (size_t)m * VDIM;
  float*       crw = out + PP_OFF + (size_t)m * VDIM;
  u16*        arow = A + (size_t)m * KP;

  if (tid < 32) { f32x4 z = {}; *(f32x4*)(out + (size_t)m * NDIM + c * 128 + tid * 4) = z; }

  u64 best = 0;  // packed (f32 bits << 32) | (0xFFFF - idx); p>0 so bits>0
#define TRK(val, idx) do { \
    u64 pk = ((u64)__float_as_uint(val) << 32) | (u64)(0xFFFFu - (u32)(idx)); \
    best = best > pk ? best : pk; } while (0)
#define GRP(cc) do {                                                     \
    f32x4u va = *(const f32x4u*)(row + (cc));                            \
    f32x4u vb = *(const f32x4u*)(row + (cc) + 4);                        \
    *(f32x4u*)(crw + (cc))     = va;                                     \
    *(f32x4u*)(crw + (cc) + 4) = vb;                                     \
    u16x8 o;                                                             \
    o[0]=f2bf(va[0]); o[1]=f2bf(va[1]); o[2]=f2bf(va[2]); o[3]=f2bf(va[3]); \
    o[4]=f2bf(vb[0]); o[5]=f2bf(vb[1]); o[6]=f2bf(vb[2]); o[7]=f2bf(vb[3]); \
    *(u16x8*)(arow + (cc)) = o;                                          \
    TRK(va[0],(cc)); TRK(va[1],(cc)+1); TRK(va[2],(cc)+2); TRK(va[3],(cc)+3); \
    TRK(vb[0],(cc)+4); TRK(vb[1],(cc)+5); TRK(vb[2],(cc)+6); TRK(vb[3],(cc)+7); \
  } while (0)

  const int ng = len >> 3;                     // 8-elem groups
  int i = tid;
  for (; i + 256 < ng; i += 512) {             // 4 loads in flight
    const int c0 = s0 + (i << 3);
    const int c1 = c0 + 2048;
    GRP(c0);
    GRP(c1);
  }
  if (i < ng) GRP(s0 + (i << 3));
  if (tid < (len & 7)) {                       // straggler elems (last chunk)
    const int col = s0 + (ng << 3) + tid;
    float v = row[col];
    crw[col] = v;
    arow[col] = f2bf(v);
    TRK(v, col);
  }
#undef GRP
#undef TRK
  if (c == 7 && tid < KP - VDIM) arow[VDIM + tid] = 0;  // K-pad (47 elems)

  __shared__ u64 sb[256];
  sb[tid] = best;
  __syncthreads();
  for (int s = 128; s > 0; s >>= 1) {
    if (tid < s) { u64 o = sb[tid + s]; if (o > sb[tid]) sb[tid] = o; }
    __syncthreads();
  }
  if (tid == 0) part[(m << 3) + c] = sb[0];    // plain store, always written
}

// ---------------------------------------------------------------------------
// convw: transpose+convert W [V][D] f32 -> ks-BLOCKED BT'[ks][1024][32] bf16
// (ks = v/32). Two adjacent 64x64 v-tiles per block = 4 ks-blocks; stores are
// 4 x 4KB fully contiguous chunks (R14-validated, +5us).
// ---------------------------------------------------------------------------
__global__ __launch_bounds__(256) void convw_kernel(const float* __restrict__ W,
                                                    u16* __restrict__ BT)
{
  __shared__ u16 tA[64][72];
  __shared__ u16 tB[64][72];
  const int cidx = blockIdx.x;        // 0..6287
  const int tid = threadIdx.x;
  const int dt  = cidx & 15;          // 16 d-tiles of 64
  const int vp  = cidx >> 4;          // 0..392 v-pairs; 393*128 == KP exactly
  const int v0  = vp << 7;
  const int d0  = dt << 6;
  const int c16 = tid & 15;
  const int r16 = tid >> 4;
#pragma unroll
  for (int p = 0; p < 4; ++p) {
    const int vl = p * 16 + r16;
    {
      const int v = v0 + vl;
      float4 w = make_float4(0.f, 0.f, 0.f, 0.f);
      if (v < VDIM) w = *(const float4*)(W + (size_t)v * NDIM + d0 + c16 * 4);
      tA[c16 * 4 + 0][vl] = f2bf(w.x);
      tA[c16 * 4 + 1][vl] = f2bf(w.y);
      tA[c16 * 4 + 2][vl] = f2bf(w.z);
      tA[c16 * 4 + 3][vl] = f2bf(w.w);
    }
    {
      const int v = v0 + 64 + vl;
      float4 w = make_float4(0.f, 0.f, 0.f, 0.f);
      if (v < VDIM) w = *(const float4*)(W + (size_t)v * NDIM + d0 + c16 * 4);
      tB[c16 * 4 + 0][vl] = f2bf(w.x);
      tB[c16 * 4 + 1][vl] = f2bf(w.y);
      tB[c16 * 4 + 2][vl] = f2bf(w.z);
      tB[c16 * 4 + 3][vl] = f2bf(w.w);
    }
  }
  __syncthreads();
  const int dl = tid >> 2;            // 0..63
  const int kq = tid & 3;             // 0..3 (8 elems each)
#pragma unroll
  for (int kb = 0; kb < 4; ++kb) {
    const u16* src = (kb < 2) ? &tA[dl][kb * 32 + kq * 8]
                              : &tB[dl][(kb - 2) * 32 + kq * 8];
    u16x8 o = *(const u16x8*)src;     // 16B-aligned (144B rows, offsets x16B)
    *(u16x8*)(BT + (size_t)((v0 >> 5) + kb) * 32768
                 + (size_t)(d0 + dl) * 32 + kq * 8) = o;
  }
}

// ---------------------------------------------------------------------------
// GEMM (R14-proven best, byte-identical schedule): 128x256 tile, BK=32,
// 8 waves (2m x 4n), ring-2 LDS (48KB -> 2 blocks/CU, grid 512 = exactly
// 2/CU), single barrier + vmcnt(0) per K-step with full-compute prefetch
// slack, paired-row 8-slot XOR swizzle (0 conflicts), split-K=32, XCD decode,
// blocked-BT' B reads (1KB contiguous per issue).
// ONLY change vs R14: TS=1 stores bf16 partials (halves epilogue + reduce
// bytes; partial rounding ~3e-7, under the bf16-input error floor).
// Block 0 also finalizes predictions from part[].
// ---------------------------------------------------------------------------
template <int TS>
__global__ __launch_bounds__(512, 4) void gemm_kernel(const u16* __restrict__ A,
                                                      const u16* __restrict__ BT,
                                                      const u64* __restrict__ part,
                                                      float* __restrict__ out,
                                                      u16* __restrict__ Pp)
{
  __shared__ u16 ldsA[2][128 * 32];   // 8KB per buf
  __shared__ u16 ldsB[2][256 * 32];   // 16KB per buf

  const int bx  = blockIdx.x;
  // decode: bx = ((kc>>3)*16 + mn)*8 + (kc&7); the 16 mn-blocks of one kc
  // share bx%8 -> same XCD (kc's A/B k-slabs stay in one L2)
  const int x   = bx & 7;
  const int s   = bx >> 3;
  const int kc  = x + ((s >> 4) << 3);   // 0..31
  const int mn  = s & 15;
  const int mt  = mn & 3;                // 4 m-tiles of 128
  const int nt  = mn >> 2;               // 4 n-tiles of 256
  const int m0  = mt << 7;
  const int n0  = nt << 8;
  const int ks0 = (kc * NST32) / KSPLIT;
  const int ks1 = ((kc + 1) * NST32) / KSPLIT;
  const int tid  = threadIdx.x;
  const int wid  = tid >> 6;
  const int lane = tid & 63;
  const int wr   = wid >> 2;   // 0..1  (m-offset wr*64)
  const int wc   = wid & 3;    // 0..3  (n-offset wc*64)

  if (bx == 0) {  // predictions: reduce 8 chunk-partials per row
    u64 best = part[tid << 3];
#pragma unroll
    for (int c = 1; c < 8; ++c) {
      u64 o = part[(tid << 3) + c];
      best = o > best ? o : best;
    }
    out[PRED_OFF + tid] = (float)(0xFFFF - (int)(best & 0xFFFFu));
  }

  // staging (pre-swizzled source): lane l = sp*8+s covers 16B slot s of 128B
  // row-pair sp within a 16-row issue; LDS written linearly; slot s of pair
  // sp holds global (row 2sp+((s^sp)>>2), kslot (s^sp)&3)  [validated R6-R15]
  const int sp   = lane >> 3;
  const int sx   = (lane & 7) ^ sp;
  const int srow = 2 * sp + (sx >> 2);        // 0..15
  const int skel = (sx & 3) << 3;
  const u16* gA = A  + (size_t)(m0 + wid * 16 + srow) * KP + skel;
  // blocked B: row stride 32 elems within a ks-frame of 1024*32 elems
  const u16* gB = BT + (size_t)(n0 + wid * 32 + srow) * 32 + skel;

  f32x4 acc[4][4] = {};

  // fragment read: row r in 16-band, kslot q4 -> swizzled slot sl
  const int r   = lane & 15;
  const int q4  = lane >> 4;
  const int sl  = (((r & 1) << 2) | q4) ^ ((r >> 1) & 7);
  const int rb2A = (wr * 64 + (r & ~1)) * 32 + sl * 8;
  const int rb2B = (wc * 64 + (r & ~1)) * 32 + sl * 8;

#define STAGE(buf, ks) do {                                              \
    gl_lds16(gA + ((size_t)(ks) << 5),     &ldsA[buf][(wid * 16) * 32]); \
    const size_t bb = (size_t)(ks) * 32768;                              \
    gl_lds16(gB + bb,                      &ldsB[buf][(wid * 32) * 32]); \
    gl_lds16(gB + bb + 512,                &ldsB[buf][(wid * 32 + 16) * 32]); \
  } while (0)

  STAGE(0, ks0);

  int b = 0;
  for (int ks = ks0; ks < ks1; ++ks) {
    asm volatile("s_waitcnt vmcnt(0)" ::: "memory");  // buf b landed (mine)
    __builtin_amdgcn_s_barrier();                     // ..and everyone's;
                                                      // also: reads of b^1 done
    if (ks + 1 < ks1) STAGE(b ^ 1, ks + 1);           // prefetch next step

    const u16* lA = ldsA[b];
    const u16* lB = ldsB[b];
    bf16x8 av[4], bv[4];
#pragma unroll
    for (int i = 0; i < 4; ++i) av[i] = *(const bf16x8*)(lA + rb2A + i * 512);
#pragma unroll
    for (int j = 0; j < 4; ++j) bv[j] = *(const bf16x8*)(lB + rb2B + j * 512);

    __builtin_amdgcn_s_setprio(1);
#pragma unroll
    for (int i = 0; i < 4; ++i)
#pragma unroll
      for (int j = 0; j < 4; ++j)
        acc[i][j] = __builtin_amdgcn_mfma_f32_16x16x32_bf16(av[i], bv[j], acc[i][j], 0, 0, 0);
    __builtin_amdgcn_s_setprio(0);
    __builtin_amdgcn_sched_barrier(0);
    b ^= 1;
  }
#undef STAGE

  const int col = lane & 15;
  if (TS) {
    // bf16 partial-tile store: Pp[bx][128][256]
    u16* pp = Pp + (size_t)bx * 32768;
#pragma unroll
    for (int i = 0; i < 4; ++i)
#pragma unroll
      for (int j = 0; j < 4; ++j)
#pragma unroll
        for (int rr = 0; rr < 4; ++rr) {
          const int mm = wr * 64 + i * 16 + q4 * 4 + rr;
          const int nn = wc * 64 + j * 16 + col;
          pp[mm * 256 + nn] = f2bf(acc[i][j][rr]);
        }
  } else {
#pragma unroll
    for (int i = 0; i < 4; ++i)
#pragma unroll
      for (int j = 0; j < 4; ++j)
#pragma unroll
        for (int rr = 0; rr < 4; ++rr) {
          const int mm = m0 + wr * 64 + i * 16 + q4 * 4 + rr;
          const int nn = n0 + wc * 64 + j * 16 + col;
          atomicAdd(out + (size_t)mm * NDIM + nn, acc[i][j][rr]);
        }
  }
}

// ---------------------------------------------------------------------------
// reduce: out[m][n] = sum over 32 kc-partials (bf16). 512 blocks x 256 thr;
// each thread owns one n-quad: 32 coalesced 8B loads + cvt, f32 accumulate.
// ---------------------------------------------------------------------------
__global__ __launch_bounds__(256) void reduce_kernel(const u16* __restrict__ Pp,
                                                     float* __restrict__ out)
{
  const int t   = blockIdx.x * 256 + threadIdx.x;  // 0..131071
  const int m   = t >> 8;                          // 0..511
  const int n0q = (t & 255) << 2;                  // 0..1020
  const int mt  = m >> 7;                          // 0..3
  const int nt  = n0q >> 8;                        // 0..3
  const size_t base = (size_t)(m & 127) * 256 + (n0q & 255);

  f32x4 sacc[2] = {};
#pragma unroll
  for (int kc = 0; kc < KSPLIT; ++kc) {
    const int bxp = (((kc >> 3) * 16 + (nt << 2) + mt) << 3) + (kc & 7);
    ushort4 v = *(const ushort4*)(Pp + (size_t)bxp * 32768 + base);
    f32x4 f = { bf2f(v.x), bf2f(v.y), bf2f(v.z), bf2f(v.w) };
    sacc[kc & 1] += f;
  }
  f32x4 rsum = sacc[0] + sacc[1];
  *(f32x4*)(out + (size_t)m * NDIM + n0q) = rsum;
}

// ---------------------------------------------------------------------------
extern "C" void kernel_launch(void* const* d_in, const int* in_sizes, int n_in,
                              void* d_out, int out_size, void* d_ws, size_t ws_size,
                              hipStream_t stream) {
  const float* P = (const float*)d_in[0];   // [512][50257]
  const float* W = (const float*)d_in[1];   // [50257][1024]
  float* out = (float*)d_out;
  u64* part = (u64*)d_ws;                               // 512 x 8 u64 (32KB)
  u16* A  = (u16*)((char*)d_ws + 65536);                // [512][KP] bf16
  u16* BT = A + (size_t)MROWS * KP;                     // BT'[1572][1024][32] bf16
  const size_t pp_off = 65536 + (size_t)MROWS * KP * 2 + (size_t)NDIM * KP * 2;
  const size_t pp_bytes = (size_t)512 * 32768 * 2;      // 33.6 MB (bf16)
  u16* Pp = (u16*)((char*)d_ws + pp_off);
  const bool two_stage = (ws_size >= pp_off + pp_bytes);

  prep_kernel<<<NPREP, 256, 0, stream>>>(P, out, A, part);
  convw_kernel<<<NCONVW, 256, 0, stream>>>(W, BT);
  if (two_stage) {
    gemm_kernel<1><<<512, 512, 0, stream>>>(A, BT, part, out, Pp);
    reduce_kernel<<<512, 256, 0, stream>>>(Pp, out);
  } else {
    gemm_kernel<0><<<512, 512, 0, stream>>>(A, BT, part, out, Pp);
  }
}